// Round 9
// baseline (152.830 us; speedup 1.0000x reference)
//
#include <hip/hip_runtime.h>

#define N_PTS 20000
#define NCLS 20
#define KNN 16
#define GRID 12
#define NCELLS (GRID * GRID * GRID)
#define HCELL (1.0f / (float)GRID)
#define CAND_CAP 640       // worst staged block: bd>=2 hs=2 clipped 5^3 E~521 +5sig
#define KEY_CAP 128        // filtered keys per point (E~26; taumax corner E~48, edge E~96)
#define R_TARGET 0.0680f   // radius giving E[cnt]~26 in the interior

__device__ __forceinline__ int cell1d(float v) {
    int c = (int)(v * (float)GRID);
    return min(max(c, 0), GRID - 1);
}

// ---------------------------------------------------------------------------
// Count (grid-wide atomics) + fused scan: last block performs the 1728-cell
// exclusive scan. Fence-free (validated rounds 2/5). Round-5 proven.
// ---------------------------------------------------------------------------
__global__ __launch_bounds__(256) void count_scan_kernel(const float* __restrict__ coords,
                                                         int* __restrict__ cellCount,
                                                         int* __restrict__ doneCtr,
                                                         int* __restrict__ cellStart,
                                                         int* __restrict__ cellCursor) {
    const int p = blockIdx.x * blockDim.x + threadIdx.x;
    if (p < N_PTS) {
        const int cx = cell1d(coords[3 * p + 0]);
        const int cy = cell1d(coords[3 * p + 1]);
        const int cz = cell1d(coords[3 * p + 2]);
        atomicAdd(&cellCount[(cz * GRID + cy) * GRID + cx], 1);
    }
    __syncthreads();                          // vmcnt(0): count RMWs retired
    __shared__ bool isLast;
    if (threadIdx.x == 0)
        isLast = (atomicAdd(doneCtr, 1) == (int)gridDim.x - 1);
    __syncthreads();
    if (!isLast) return;

    __shared__ int part[256];
    const int t = threadIdx.x;
    const int base = t * 7;                   // 256*7 = 1792 >= 1728
    int local[7];
    int s = 0;
#pragma unroll
    for (int i = 0; i < 7; ++i) {
        const int c = base + i;
        const int v = (c < NCELLS)
            ? __hip_atomic_load(&cellCount[c], __ATOMIC_RELAXED, __HIP_MEMORY_SCOPE_AGENT)
            : 0;
        local[i] = s;
        s += v;
    }
    part[t] = s;
    __syncthreads();
    for (int off = 1; off < 256; off <<= 1) {
        const int v = part[t] + ((t >= off) ? part[t - off] : 0);
        __syncthreads();
        part[t] = v;
        __syncthreads();
    }
    const int excl = (t > 0) ? part[t - 1] : 0;
#pragma unroll
    for (int i = 0; i < 7; ++i) {
        const int c = base + i;
        if (c < NCELLS) {
            cellStart[c] = excl + local[i];
            cellCursor[c] = excl + local[i];
        }
    }
    if (t == 255) cellStart[NCELLS] = part[255];
}

// ---------------------------------------------------------------------------
// Scatter (counting sort) + gather logits row + FUSED softmax -> q0s, ls.
// Round-5 proven.
// ---------------------------------------------------------------------------
__global__ __launch_bounds__(256) void scatter_kernel(const float* __restrict__ coords,
                                                      const float* __restrict__ logits,
                                                      int* __restrict__ cellCursor,
                                                      float4* __restrict__ sortedPts,
                                                      int* __restrict__ orig,
                                                      float* __restrict__ ls,
                                                      float* __restrict__ q0s) {
    const int p = blockIdx.x * blockDim.x + threadIdx.x;
    if (p >= N_PTS) return;
    const float x = coords[3 * p + 0];
    const float y = coords[3 * p + 1];
    const float z = coords[3 * p + 2];
    const int c = (cell1d(z) * GRID + cell1d(y)) * GRID + cell1d(x);
    const int pos = atomicAdd(&cellCursor[c], 1);
    sortedPts[pos] = make_float4(x, y, z, __uint_as_float((unsigned)p));
    orig[pos] = p;
    const float4* l4 = (const float4*)(logits + p * NCLS);
    float v[NCLS];
#pragma unroll
    for (int u = 0; u < 5; ++u) {
        const float4 a = l4[u];
        v[4 * u + 0] = a.x; v[4 * u + 1] = a.y;
        v[4 * u + 2] = a.z; v[4 * u + 3] = a.w;
    }
    float4* d4 = (float4*)(ls + pos * NCLS);
#pragma unroll
    for (int u = 0; u < 5; ++u)
        d4[u] = make_float4(v[4 * u], v[4 * u + 1], v[4 * u + 2], v[4 * u + 3]);
    float mx = v[0];
#pragma unroll
    for (int cc = 1; cc < NCLS; ++cc) mx = fmaxf(mx, v[cc]);
    float sum = 0.f;
#pragma unroll
    for (int cc = 0; cc < NCLS; ++cc) { v[cc] = __expf(v[cc] - mx); sum += v[cc]; }
    const float inv = 1.f / sum;
    float4* q4 = (float4*)(q0s + pos * NCLS);
#pragma unroll
    for (int u = 0; u < 5; ++u)
        q4[u] = make_float4(v[4 * u] * inv, v[4 * u + 1] * inv,
                            v[4 * u + 2] * inv, v[4 * u + 3] * inv);
}

// ---------------------------------------------------------------------------
// Rare exact fallback: wave-cooperative global-memory ladder (hw growing).
// Inline (round-4 data: separate queue dispatch was +20us vs inline).
// ---------------------------------------------------------------------------
__device__ void knn_ladder(const float4* __restrict__ sortedPts,
                           const int* __restrict__ cellStart,
                           const float4 qp, const int s, int hw,
                           unsigned long long* keys, const int lane,
                           int* __restrict__ knn_out) {
    const unsigned long long laneLt = (1ull << lane) - 1ull;
    const int cx = cell1d(qp.x), cy = cell1d(qp.y), cz = cell1d(qp.z);
    float g = 0.9995f * (float)hw * HCELL;
    float tau = g * g;
    int cnt = 0;
    for (int att = 0; att < 16; ++att) {
        cnt = 0;
        const int xlo = max(cx - hw, 0), xhi = min(cx + hw, GRID - 1);
        const int ylo = max(cy - hw, 0), yhi = min(cy + hw, GRID - 1);
        const int zlo = max(cz - hw, 0), zhi = min(cz + hw, GRID - 1);
        for (int zz = zlo; zz <= zhi; ++zz) {
            for (int yy = ylo; yy <= yhi; ++yy) {
                const int rowc = (zz * GRID + yy) * GRID;
                const int beg = cellStart[rowc + xlo];
                const int end = cellStart[rowc + xhi + 1];
                for (int j0 = beg; j0 < end; j0 += 64) {
                    const int j = j0 + lane;
                    const bool jv = j < end;
                    const float4 pt = sortedPts[jv ? j : beg];
                    const float dx = pt.x - qp.x, dy = pt.y - qp.y, dz = pt.z - qp.z;
                    const float d2 = dx * dx + dy * dy + dz * dz;
                    const bool take = jv && (d2 < tau);
                    const unsigned long long mm = __ballot(take);
                    if (take) {
                        const int pos = cnt + (int)__popcll(mm & laneLt);
                        if (pos < KEY_CAP)
                            keys[pos] = (((unsigned long long)__float_as_uint(d2)) << 32) |
                                        (unsigned long long)(unsigned)j;
                    }
                    cnt += (int)__popcll(mm);
                }
            }
        }
        if (cnt >= KNN && cnt <= KEY_CAP) break;
        if (cnt < KNN) {
            if (hw < GRID - 1) { ++hw; g = 0.9995f * (float)hw * HCELL; tau = g * g; }
            else tau *= 2.5f;
        } else {
            tau *= 0.6f;
        }
    }
    const int m = min(cnt, KEY_CAP);
    const unsigned long long k0 = (lane < m) ? keys[lane] : ~0ull;
    const unsigned long long k1 = (lane + 64 < m) ? keys[lane + 64] : ~0ull;
    int r0 = 0, r1 = 0;
    for (int j = 0; j < m; ++j) {
        const unsigned long long kj = keys[j];
        r0 += (kj < k0); r1 += (kj < k1);
    }
    if (lane < m && r0 < KNN)      knn_out[s * KNN + r0] = (int)(unsigned)(k0 & 0xffffffffull);
    if (lane + 64 < m && r1 < KNN) knn_out[s * KNN + r1] = (int)(unsigned)(k1 & 0xffffffffull);
}

// ---------------------------------------------------------------------------
// kNN + CRF iter 1, ONE block per cell. __launch_bounds__(256, 8) pins 8
// waves/SIMD => compiler must stay <= 64 VGPR (the occupancy cliff, m69):
// round 6's unconstrained fusion hit 88 VGPR -> 4 blocks/CU -> 2 scheduling
// batches -> 2x knn time. CRF tail is register-lean: two-pass acc[10] with
// immediate fold into ref[5]. Tail also FILLS the knn straggler bubble
// (early blocks crf while ladder blocks still knn).
// ---------------------------------------------------------------------------
__global__ __launch_bounds__(256, 8) void knn_crf1_kernel(const float4* __restrict__ sortedPts,
                                                          const int* __restrict__ cellStart,
                                                          const float* __restrict__ ls,
                                                          const float* __restrict__ W,
                                                          const float* __restrict__ q0s,
                                                          int* __restrict__ knn_out,
                                                          float* __restrict__ q1s) {
    __shared__ float4 cand[CAND_CAP];                 // 10.24 KB
    __shared__ unsigned long long keys[4][KEY_CAP];   // 4 KB
    __shared__ float Ws[NCLS * NCLS];                 // 1.6 KB
    const int lane = threadIdx.x & 63;
    const int wave = threadIdx.x >> 6;
    const int c = blockIdx.x;
    const int cz = c / (GRID * GRID);
    const int cy = (c / GRID) % GRID;
    const int cx = c % GRID;
    const int pbeg = cellStart[c];
    const int pend = cellStart[c + 1];
    const int npts = pend - pbeg;
    if (npts <= 0) return;
    for (int i = threadIdx.x; i < NCLS * NCLS; i += 256) Ws[i] = W[i];
    const int bd = (cx == 0 || cx == GRID - 1) + (cy == 0 || cy == GRID - 1) +
                   (cz == 0 || cz == GRID - 1);
    const int hs = (bd >= 2) ? 2 : 1;                 // staging halo width
    const unsigned long long laneLt = (1ull << lane) - 1ull;

    const int xlo = max(cx - hs, 0), xhi = min(cx + hs, GRID - 1);
    const int ylo = max(cy - hs, 0), yhi = min(cy + hs, GRID - 1);
    const int zlo = max(cz - hs, 0), zhi = min(cz + hs, GRID - 1);
    const int ny = yhi - ylo + 1;
    const int nruns = (zhi - zlo + 1) * ny;           // <= 25 x-contiguous runs

    int beg = 0, len = 0;
    if (lane < nruns) {
        const int zz = zlo + lane / ny;
        const int yy = ylo + lane % ny;
        const int rowc = (zz * GRID + yy) * GRID;
        beg = cellStart[rowc + xlo];
        len = cellStart[rowc + xhi + 1] - beg;
    }
    int off = len;
#pragma unroll
    for (int sh = 1; sh < 32; sh <<= 1) {
        const int o = __shfl_up(off, sh, 64);
        if (lane >= sh) off += o;
    }
    const int nc = __shfl(off, nruns - 1);
    off -= len;                                        // exclusive
    const int ownRun = (cz - zlo) * ny + (cy - ylo);
    const int ownOff = __shfl(off, ownRun) + (pbeg - __shfl(beg, ownRun));

    if (nc <= CAND_CAP) {
        for (int r = wave; r < nruns; r += 4) {
            const int rb = __shfl(beg, r);
            const int rl = __shfl(len, r);
            const int ro = __shfl(off, r);
            for (int i = lane; i < rl; i += 64) {
                float4 pt = sortedPts[rb + i];
                pt.w = __uint_as_float((unsigned)(rb + i));
                cand[ro + i] = pt;
            }
        }
    }
    __syncthreads();

    if (nc > CAND_CAP) {                               // ~never (>5 sigma)
        for (int idx = wave; idx < npts; idx += 4)
            knn_ladder(sortedPts, cellStart, sortedPts[pbeg + idx], pbeg + idx,
                       hs, keys[wave], lane, knn_out);
    } else {
        const float taumaxr = 0.9995f * (float)hs * HCELL;
        const float taumax = taumaxr * taumaxr;

        for (int idx = wave; idx < npts; idx += 4) {
            const int s = pbeg + idx;
            const float4 qp = cand[ownOff + idx];
            // boundary-corrected tau targeting E[cnt]~26, capped at hs*h
            float r = R_TARGET;
            const float inv2r = 0.5f / r;
            const float fx = (fminf(qp.x + r, 1.f) - fmaxf(qp.x - r, 0.f)) * inv2r;
            const float fy = (fminf(qp.y + r, 1.f) - fmaxf(qp.y - r, 0.f)) * inv2r;
            const float fz = (fminf(qp.z + r, 1.f) - fmaxf(qp.z - r, 0.f)) * inv2r;
            const float f = fmaxf(fx * fy * fz, 0.05f);
            r = R_TARGET * __powf(f, -0.33333334f);
            float tau = fminf(r * r, taumax);
            bool triedMax = (tau >= taumax * 0.999f);

            int cnt = 0;
            bool ok = false;
            for (int att = 0; att < 5 && !ok; ++att) {
                cnt = 0;
                for (int j0 = 0; j0 < nc; j0 += 64) {
                    const int j = j0 + lane;
                    float d2 = 1e30f;
                    unsigned pw = 0;
                    if (j < nc) {
                        const float4 pt = cand[j];
                        const float dx = pt.x - qp.x, dy = pt.y - qp.y, dz = pt.z - qp.z;
                        d2 = dx * dx + dy * dy + dz * dz;
                        pw = __float_as_uint(pt.w);
                    }
                    const bool take = d2 < tau;
                    const unsigned long long mm = __ballot(take);
                    if (take) {
                        const int pos = cnt + (int)__popcll(mm & laneLt);
                        if (pos < KEY_CAP)
                            keys[wave][pos] =
                                (((unsigned long long)__float_as_uint(d2)) << 32) |
                                (unsigned long long)pw;
                    }
                    cnt += (int)__popcll(mm);
                }
                if (cnt >= KNN && cnt <= KEY_CAP) ok = true;
                else if (cnt < KNN) {
                    if (triedMax) break;               // needs radius > hs*h
                    tau = taumax; triedMax = true;
                } else tau *= 0.6f;
            }
            if (!ok) {                                 // rare Poisson-tail points
                knn_ladder(sortedPts, cellStart, qp, s, hs + 1, keys[wave], lane, knn_out);
                continue;
            }
            const int m = cnt;
            const unsigned long long k0 = (lane < m) ? keys[wave][lane] : ~0ull;
            const unsigned long long k1 = (lane + 64 < m) ? keys[wave][lane + 64] : ~0ull;
            int r0 = 0, r1 = 0;
            for (int j = 0; j < m; ++j) {
                const unsigned long long kj = keys[wave][j];   // LDS broadcast
                r0 += (kj < k0); r1 += (kj < k1);
            }
            if (lane < m && r0 < KNN)
                knn_out[s * KNN + r0] = (int)(unsigned)(k0 & 0xffffffffull);
            if (lane + 64 < m && r1 < KNN)
                knn_out[s * KNN + r1] = (int)(unsigned)(k1 & 0xffffffffull);
        }
    }
    __syncthreads();     // all knn rows for this cell written (incl. ladders)

    // ---- fused CRF iteration 1, register-lean (two-pass acc[10]) ----
    const int g = lane >> 2;
    const int sub = lane & 3;
    const int c0 = sub * 5;
    for (int idx = wave * 16 + g; idx < npts; idx += 64) {
        const int s = pbeg + idx;
        const int4 k4 = ((const int4*)(knn_out + s * KNN))[sub];
        float ref[5];
#pragma unroll
        for (int i = 0; i < 5; ++i) ref[i] = ls[s * NCLS + c0 + i];
#pragma unroll
        for (int half = 0; half < 2; ++half) {
            float acc[10];
#pragma unroll
            for (int i = 0; i < 10; ++i) acc[i] = 0.f;
            const int ids[4] = {k4.x, k4.y, k4.z, k4.w};
#pragma unroll
            for (int u = 0; u < 4; ++u) {
                unsigned id = (unsigned)ids[u];
                if (id >= N_PTS) id = 0;   // safety clamp (unreachable)
                const float2* r2 = (const float2*)(q0s + id * NCLS) + half * 5;
#pragma unroll
                for (int v = 0; v < 5; ++v) {
                    const float2 a = r2[v];
                    acc[2 * v + 0] += a.x;
                    acc[2 * v + 1] += a.y;
                }
            }
#pragma unroll
            for (int k = 0; k < 10; ++k) {
                acc[k] += __shfl_xor(acc[k], 1, 64);
                acc[k] += __shfl_xor(acc[k], 2, 64);
            }
#pragma unroll
            for (int i = 0; i < 5; ++i) {
                float sv = 0.f;
#pragma unroll
                for (int k = 0; k < 10; ++k)
                    sv += acc[k] * Ws[(c0 + i) * NCLS + half * 10 + k];
                ref[i] += sv * (1.f / 16.f);           // msg mean folded here
            }
        }
        float mx = ref[0];
#pragma unroll
        for (int i = 1; i < 5; ++i) mx = fmaxf(mx, ref[i]);
        mx = fmaxf(mx, __shfl_xor(mx, 1, 64));
        mx = fmaxf(mx, __shfl_xor(mx, 2, 64));
        float ex[5];
        float ps = 0.f;
#pragma unroll
        for (int i = 0; i < 5; ++i) { ex[i] = __expf(ref[i] - mx); ps += ex[i]; }
        ps += __shfl_xor(ps, 1, 64);
        ps += __shfl_xor(ps, 2, 64);
        const float inv = 1.f / ps;
#pragma unroll
        for (int i = 0; i < 5; ++i) q1s[s * NCLS + c0 + i] = ex[i] * inv;
    }
}

// ---------------------------------------------------------------------------
// CRF iteration, SORTED space, 8 lanes/point (round-8, neutral-verified).
// Used for iterations 2 and 3.
// ---------------------------------------------------------------------------
__global__ __launch_bounds__(256) void crf_iter_kernel(const float* __restrict__ ls,
                                                       const float* __restrict__ W,
                                                       const int* __restrict__ knn,
                                                       const float* __restrict__ qin,
                                                       float* __restrict__ qout,
                                                       const int* __restrict__ orig,
                                                       float* __restrict__ outRef,
                                                       float* __restrict__ outQ) {
    __shared__ float Ws[NCLS * NCLS];
    for (int i = threadIdx.x; i < NCLS * NCLS; i += blockDim.x) Ws[i] = W[i];
    __syncthreads();
    const int t = blockIdx.x * blockDim.x + threadIdx.x;
    const int p = t >> 3;
    const int sub = t & 7;
    if (p >= N_PTS) return;

    float acc[NCLS];
#pragma unroll
    for (int c = 0; c < NCLS; ++c) acc[c] = 0.f;

    const int2 k2 = ((const int2*)(knn + p * KNN))[sub];
    const int ids[2] = {k2.x, k2.y};
#pragma unroll
    for (int u = 0; u < 2; ++u) {
        unsigned id = (unsigned)ids[u];
        if (id >= N_PTS) id = 0;        // safety clamp (unreachable)
        const float4* r4 = (const float4*)(qin + id * NCLS);
#pragma unroll
        for (int v = 0; v < 5; ++v) {
            const float4 a = r4[v];
            acc[4 * v + 0] += a.x; acc[4 * v + 1] += a.y;
            acc[4 * v + 2] += a.z; acc[4 * v + 3] += a.w;
        }
    }
#pragma unroll
    for (int c = 0; c < NCLS; ++c) {
        acc[c] += __shfl_xor(acc[c], 1, 64);
        acc[c] += __shfl_xor(acc[c], 2, 64);
        acc[c] += __shfl_xor(acc[c], 4, 64);
        acc[c] *= (1.f / 16.f);          // msg (sum over all 16 neighbours)
    }

    const int c0 = (sub & 3) * 5;        // sub and sub+4 duplicate this block
    float ref[5];
#pragma unroll
    for (int i = 0; i < 5; ++i) {
        float s = ls[p * NCLS + c0 + i];
#pragma unroll
        for (int k = 0; k < NCLS; ++k) s += acc[k] * Ws[(c0 + i) * NCLS + k];  // x@W^T
        ref[i] = s;
    }

    float mx = ref[0];
#pragma unroll
    for (int i = 1; i < 5; ++i) mx = fmaxf(mx, ref[i]);
    mx = fmaxf(mx, __shfl_xor(mx, 1, 64));   // halves hold identical values,
    mx = fmaxf(mx, __shfl_xor(mx, 2, 64));   // so xor1,2 gives the full max
    float ex[5];
    float ps = 0.f;
#pragma unroll
    for (int i = 0; i < 5; ++i) { ex[i] = __expf(ref[i] - mx); ps += ex[i]; }
    ps += __shfl_xor(ps, 1, 64);
    ps += __shfl_xor(ps, 2, 64);
    const float inv = 1.f / ps;

    if (sub < 4) {                        // mirror half skips stores
        if (outRef != nullptr) {
            const int o = orig[p];
#pragma unroll
            for (int i = 0; i < 5; ++i) {
                outRef[o * NCLS + c0 + i] = ref[i];
                outQ[o * NCLS + c0 + i] = ex[i] * inv;
            }
        } else {
#pragma unroll
            for (int i = 0; i < 5; ++i) qout[p * NCLS + c0 + i] = ex[i] * inv;
        }
    }
}

// ---------------------------------------------------------------------------
extern "C" void kernel_launch(void* const* d_in, const int* in_sizes, int n_in,
                              void* d_out, int out_size, void* d_ws, size_t ws_size,
                              hipStream_t stream) {
    const float* logits = (const float*)d_in[0];   // (20000, 20)
    const float* coords = (const float*)d_in[1];   // (20000, 3)
    const float* W      = (const float*)d_in[2];   // (20, 20)
    float* out = (float*)d_out;                    // refined (400000) | q (400000)

    // workspace (~5 MB); q1s aliases out's q-region (safe: final pass reads
    // only q0s/ls/knn/orig and overwrites that region last).
    char* ws = (char*)d_ws;
    size_t off = 0;
    int* knn = (int*)(ws + off);              off += (size_t)N_PTS * KNN * 4;
    off = (off + 255) & ~(size_t)255;
    float* ls = (float*)(ws + off);           off += (size_t)N_PTS * NCLS * 4;
    off = (off + 255) & ~(size_t)255;
    float* q0s = (float*)(ws + off);          off += (size_t)N_PTS * NCLS * 4;
    off = (off + 255) & ~(size_t)255;
    float4* sortedPts = (float4*)(ws + off);  off += (size_t)N_PTS * 16;
    off = (off + 255) & ~(size_t)255;
    int* orig = (int*)(ws + off);             off += (size_t)N_PTS * 4;
    off = (off + 255) & ~(size_t)255;
    int* cellCount = (int*)(ws + off);        off += (size_t)(NCELLS + 1) * 4;
    int* doneCtr   = cellCount + NCELLS;      // zeroed with cellCount
    off = (off + 255) & ~(size_t)255;
    int* cellStart = (int*)(ws + off);        off += (size_t)(NCELLS + 1) * 4;
    off = (off + 255) & ~(size_t)255;
    int* cellCursor = (int*)(ws + off);
    float* q1s = out + N_PTS * NCLS;

    const int threads = 256;
    const int pblocks = (N_PTS + threads - 1) / threads;      // 79
    const int cblocks = (8 * N_PTS + threads - 1) / threads;  // 625 (8 lanes/pt)

    hipMemsetAsync(cellCount, 0, (NCELLS + 1) * sizeof(int), stream);
    count_scan_kernel<<<pblocks, threads, 0, stream>>>(coords, cellCount, doneCtr,
                                                       cellStart, cellCursor);
    scatter_kernel<<<pblocks, threads, 0, stream>>>(coords, logits, cellCursor,
                                                    sortedPts, orig, ls, q0s);
    knn_crf1_kernel<<<NCELLS, threads, 0, stream>>>(sortedPts, cellStart, ls, W,
                                                    q0s, knn, q1s);
    crf_iter_kernel<<<cblocks, threads, 0, stream>>>(ls, W, knn, q1s, q0s, orig,
                                                     nullptr, nullptr);
    crf_iter_kernel<<<cblocks, threads, 0, stream>>>(ls, W, knn, q0s, nullptr, orig,
                                                     out, out + N_PTS * NCLS);
}

// Round 10
// 125.023 us; speedup vs baseline: 1.2224x; 1.2224x over previous
//
#include <hip/hip_runtime.h>

#define N_PTS 20000
#define NCLS 20
#define KNN 16
#define GRID 12
#define NCELLS (GRID * GRID * GRID)
#define HCELL (1.0f / (float)GRID)
#define CAND_CAP 640       // worst staged block: bd>=2 hs=2 clipped 5^3 E~521 +5sig
#define KEY_CAP 128        // filtered keys per point (E~26; taumax corner E~48, edge E~96)
#define R_TARGET 0.0680f   // radius giving E[cnt]~26 in the interior

__device__ __forceinline__ int cell1d(float v) {
    int c = (int)(v * (float)GRID);
    return min(max(c, 0), GRID - 1);
}

// ---------------------------------------------------------------------------
// FUSED build: count (grid atomics) + last-block 1728-cell scan + fence-free
// readyFlag handshake + scatter + softmax -> q0s, ls. 79 blocks, all
// trivially co-resident; the spin lasts only as long as the last-block scan
// (~3us) which was on the critical path anyway as a separate dispatch.
// Correctness validated in round 2 (passed); fence-free discipline validated
// rounds 2/5/8: count RMWs drain at __syncthreads before the doneCtr RMW;
// cellCursor init uses sc1 stores, its consumers are coherent RMWs;
// cellStart (plain stores) is consumed by the NEXT kernel (end-of-kernel
// flush). NOTE round-6/9 lesson: do NOT fuse the CRF tail here -- but this
// fusion adds no register pressure (scan phase is int-only).
// ---------------------------------------------------------------------------
__global__ __launch_bounds__(256) void build_kernel(const float* __restrict__ coords,
                                                    const float* __restrict__ logits,
                                                    int* __restrict__ cellCount,
                                                    int* __restrict__ doneCtr,
                                                    int* __restrict__ readyFlag,
                                                    int* __restrict__ cellStart,
                                                    int* __restrict__ cellCursor,
                                                    float4* __restrict__ sortedPts,
                                                    int* __restrict__ orig,
                                                    float* __restrict__ ls,
                                                    float* __restrict__ q0s) {
    const int p = blockIdx.x * blockDim.x + threadIdx.x;
    const bool act = (p < N_PTS);
    float x = 0.f, y = 0.f, z = 0.f;
    int c = 0;
    if (act) {
        x = coords[3 * p + 0];
        y = coords[3 * p + 1];
        z = coords[3 * p + 2];
        c = (cell1d(z) * GRID + cell1d(y)) * GRID + cell1d(x);
        atomicAdd(&cellCount[c], 1);          // coherent RMW
    }
    __syncthreads();                          // vmcnt(0): count RMWs retired
    __shared__ bool isLast;
    if (threadIdx.x == 0)
        isLast = (atomicAdd(doneCtr, 1) == (int)gridDim.x - 1);
    __syncthreads();

    if (isLast) {
        __shared__ int part[256];
        const int t = threadIdx.x;
        const int base = t * 7;               // 256*7 = 1792 >= 1728
        int local[7];
        int s = 0;
#pragma unroll
        for (int i = 0; i < 7; ++i) {
            const int cc = base + i;
            const int v = (cc < NCELLS)
                ? __hip_atomic_load(&cellCount[cc], __ATOMIC_RELAXED, __HIP_MEMORY_SCOPE_AGENT)
                : 0;
            local[i] = s;
            s += v;
        }
        part[t] = s;
        __syncthreads();
        for (int off2 = 1; off2 < 256; off2 <<= 1) {
            const int v = part[t] + ((t >= off2) ? part[t - off2] : 0);
            __syncthreads();
            part[t] = v;
            __syncthreads();
        }
        const int excl = (t > 0) ? part[t - 1] : 0;
#pragma unroll
        for (int i = 0; i < 7; ++i) {
            const int cc = base + i;
            if (cc < NCELLS) {
                cellStart[cc] = excl + local[i];          // for next kernel
                __hip_atomic_store(&cellCursor[cc], excl + local[i],
                                   __ATOMIC_RELAXED, __HIP_MEMORY_SCOPE_AGENT);
            }
        }
        if (t == 255) cellStart[NCELLS] = part[255];
        __syncthreads();                      // cursor sc1 stores at L3
        if (t == 0)
            __hip_atomic_store(readyFlag, 1, __ATOMIC_RELAXED, __HIP_MEMORY_SCOPE_AGENT);
    }
    if (threadIdx.x == 0) {
        while (__hip_atomic_load(readyFlag, __ATOMIC_RELAXED, __HIP_MEMORY_SCOPE_AGENT) == 0)
            __builtin_amdgcn_s_sleep(2);
    }
    __syncthreads();
    if (!act) return;

    // ---- scatter phase (coords/cell already in registers) ----
    const int pos = atomicAdd(&cellCursor[c], 1);   // coherent RMW sees sc1 init
    sortedPts[pos] = make_float4(x, y, z, __uint_as_float((unsigned)p));
    orig[pos] = p;
    const float4* l4 = (const float4*)(logits + p * NCLS);
    float v[NCLS];
#pragma unroll
    for (int u = 0; u < 5; ++u) {
        const float4 a = l4[u];
        v[4 * u + 0] = a.x; v[4 * u + 1] = a.y;
        v[4 * u + 2] = a.z; v[4 * u + 3] = a.w;
    }
    float4* d4 = (float4*)(ls + pos * NCLS);
#pragma unroll
    for (int u = 0; u < 5; ++u)
        d4[u] = make_float4(v[4 * u], v[4 * u + 1], v[4 * u + 2], v[4 * u + 3]);
    float mx = v[0];
#pragma unroll
    for (int cc2 = 1; cc2 < NCLS; ++cc2) mx = fmaxf(mx, v[cc2]);
    float sum = 0.f;
#pragma unroll
    for (int cc2 = 0; cc2 < NCLS; ++cc2) { v[cc2] = __expf(v[cc2] - mx); sum += v[cc2]; }
    const float inv = 1.f / sum;
    float4* q4 = (float4*)(q0s + pos * NCLS);
#pragma unroll
    for (int u = 0; u < 5; ++u)
        q4[u] = make_float4(v[4 * u] * inv, v[4 * u + 1] * inv,
                            v[4 * u + 2] * inv, v[4 * u + 3] * inv);
}

// ---------------------------------------------------------------------------
// Rare exact fallback: wave-cooperative global-memory ladder (hw growing).
// Inline (round-4 data: separate queue dispatch was +20us vs inline).
// ---------------------------------------------------------------------------
__device__ void knn_ladder(const float4* __restrict__ sortedPts,
                           const int* __restrict__ cellStart,
                           const float4 qp, const int s, int hw,
                           unsigned long long* keys, const int lane,
                           int* __restrict__ knn_out) {
    const unsigned long long laneLt = (1ull << lane) - 1ull;
    const int cx = cell1d(qp.x), cy = cell1d(qp.y), cz = cell1d(qp.z);
    float g = 0.9995f * (float)hw * HCELL;
    float tau = g * g;
    int cnt = 0;
    for (int att = 0; att < 16; ++att) {
        cnt = 0;
        const int xlo = max(cx - hw, 0), xhi = min(cx + hw, GRID - 1);
        const int ylo = max(cy - hw, 0), yhi = min(cy + hw, GRID - 1);
        const int zlo = max(cz - hw, 0), zhi = min(cz + hw, GRID - 1);
        for (int zz = zlo; zz <= zhi; ++zz) {
            for (int yy = ylo; yy <= yhi; ++yy) {
                const int rowc = (zz * GRID + yy) * GRID;
                const int beg = cellStart[rowc + xlo];
                const int end = cellStart[rowc + xhi + 1];
                for (int j0 = beg; j0 < end; j0 += 64) {
                    const int j = j0 + lane;
                    const bool jv = j < end;
                    const float4 pt = sortedPts[jv ? j : beg];
                    const float dx = pt.x - qp.x, dy = pt.y - qp.y, dz = pt.z - qp.z;
                    const float d2 = dx * dx + dy * dy + dz * dz;
                    const bool take = jv && (d2 < tau);
                    const unsigned long long mm = __ballot(take);
                    if (take) {
                        const int pos = cnt + (int)__popcll(mm & laneLt);
                        if (pos < KEY_CAP)
                            keys[pos] = (((unsigned long long)__float_as_uint(d2)) << 32) |
                                        (unsigned long long)(unsigned)j;
                    }
                    cnt += (int)__popcll(mm);
                }
            }
        }
        if (cnt >= KNN && cnt <= KEY_CAP) break;
        if (cnt < KNN) {
            if (hw < GRID - 1) { ++hw; g = 0.9995f * (float)hw * HCELL; tau = g * g; }
            else tau *= 2.5f;
        } else {
            tau *= 0.6f;
        }
    }
    const int m = min(cnt, KEY_CAP);
    const unsigned long long k0 = (lane < m) ? keys[lane] : ~0ull;
    const unsigned long long k1 = (lane + 64 < m) ? keys[lane + 64] : ~0ull;
    int r0 = 0, r1 = 0;
    for (int j = 0; j < m; ++j) {
        const unsigned long long kj = keys[j];
        r0 += (kj < k0); r1 += (kj < k1);
    }
    if (lane < m && r0 < KNN)      knn_out[s * KNN + r0] = (int)(unsigned)(k0 & 0xffffffffull);
    if (lane + 64 < m && r1 < KNN) knn_out[s * KNN + r1] = (int)(unsigned)(k1 & 0xffffffffull);
}

// ---------------------------------------------------------------------------
// kNN: ONE block per cell, round-5/8 version VERBATIM (28 VGPR -> 8
// blocks/CU, whole 1728-block grid co-resident in a single batch).
// Rounds 6/9 proved fusing the CRF tail here loses either way (occupancy tax
// at 88 VGPR, spill tax at 32) -- keep this kernel pure.
// ---------------------------------------------------------------------------
__global__ __launch_bounds__(256) void knn_kernel(const float4* __restrict__ sortedPts,
                                                  const int* __restrict__ cellStart,
                                                  int* __restrict__ knn_out) {
    __shared__ float4 cand[CAND_CAP];                 // 10.24 KB
    __shared__ unsigned long long keys[4][KEY_CAP];   // 4 KB
    const int lane = threadIdx.x & 63;
    const int wave = threadIdx.x >> 6;
    const int c = blockIdx.x;
    const int cz = c / (GRID * GRID);
    const int cy = (c / GRID) % GRID;
    const int cx = c % GRID;
    const int pbeg = cellStart[c];
    const int pend = cellStart[c + 1];
    const int npts = pend - pbeg;
    if (npts <= 0) return;
    const int bd = (cx == 0 || cx == GRID - 1) + (cy == 0 || cy == GRID - 1) +
                   (cz == 0 || cz == GRID - 1);
    const int hs = (bd >= 2) ? 2 : 1;                 // staging halo width
    const unsigned long long laneLt = (1ull << lane) - 1ull;

    const int xlo = max(cx - hs, 0), xhi = min(cx + hs, GRID - 1);
    const int ylo = max(cy - hs, 0), yhi = min(cy + hs, GRID - 1);
    const int zlo = max(cz - hs, 0), zhi = min(cz + hs, GRID - 1);
    const int ny = yhi - ylo + 1;
    const int nruns = (zhi - zlo + 1) * ny;           // <= 25 x-contiguous runs

    int beg = 0, len = 0;
    if (lane < nruns) {
        const int zz = zlo + lane / ny;
        const int yy = ylo + lane % ny;
        const int rowc = (zz * GRID + yy) * GRID;
        beg = cellStart[rowc + xlo];
        len = cellStart[rowc + xhi + 1] - beg;
    }
    int off = len;
#pragma unroll
    for (int sh = 1; sh < 32; sh <<= 1) {
        const int o = __shfl_up(off, sh, 64);
        if (lane >= sh) off += o;
    }
    const int nc = __shfl(off, nruns - 1);
    off -= len;                                        // exclusive
    const int ownRun = (cz - zlo) * ny + (cy - ylo);
    const int ownOff = __shfl(off, ownRun) + (pbeg - __shfl(beg, ownRun));

    if (nc <= CAND_CAP) {
        for (int r = wave; r < nruns; r += 4) {
            const int rb = __shfl(beg, r);
            const int rl = __shfl(len, r);
            const int ro = __shfl(off, r);
            for (int i = lane; i < rl; i += 64) {
                float4 pt = sortedPts[rb + i];
                pt.w = __uint_as_float((unsigned)(rb + i));
                cand[ro + i] = pt;
            }
        }
    }
    __syncthreads();

    if (nc > CAND_CAP) {                               // ~never (>5 sigma)
        for (int idx = wave; idx < npts; idx += 4)
            knn_ladder(sortedPts, cellStart, sortedPts[pbeg + idx], pbeg + idx,
                       hs, keys[wave], lane, knn_out);
        return;
    }

    const float taumaxr = 0.9995f * (float)hs * HCELL;
    const float taumax = taumaxr * taumaxr;

    for (int idx = wave; idx < npts; idx += 4) {
        const int s = pbeg + idx;
        const float4 qp = cand[ownOff + idx];
        // boundary-corrected tau targeting E[cnt]~26, capped at coverage hs*h
        float r = R_TARGET;
        const float inv2r = 0.5f / r;
        const float fx = (fminf(qp.x + r, 1.f) - fmaxf(qp.x - r, 0.f)) * inv2r;
        const float fy = (fminf(qp.y + r, 1.f) - fmaxf(qp.y - r, 0.f)) * inv2r;
        const float fz = (fminf(qp.z + r, 1.f) - fmaxf(qp.z - r, 0.f)) * inv2r;
        const float f = fmaxf(fx * fy * fz, 0.05f);
        r = R_TARGET * __powf(f, -0.33333334f);
        float tau = fminf(r * r, taumax);
        bool triedMax = (tau >= taumax * 0.999f);

        int cnt = 0;
        bool ok = false;
        for (int att = 0; att < 5 && !ok; ++att) {
            cnt = 0;
            for (int j0 = 0; j0 < nc; j0 += 64) {
                const int j = j0 + lane;
                float d2 = 1e30f;
                unsigned pw = 0;
                if (j < nc) {
                    const float4 pt = cand[j];
                    const float dx = pt.x - qp.x, dy = pt.y - qp.y, dz = pt.z - qp.z;
                    d2 = dx * dx + dy * dy + dz * dz;
                    pw = __float_as_uint(pt.w);
                }
                const bool take = d2 < tau;
                const unsigned long long mm = __ballot(take);
                if (take) {
                    const int pos = cnt + (int)__popcll(mm & laneLt);
                    if (pos < KEY_CAP)
                        keys[wave][pos] =
                            (((unsigned long long)__float_as_uint(d2)) << 32) |
                            (unsigned long long)pw;
                }
                cnt += (int)__popcll(mm);
            }
            if (cnt >= KNN && cnt <= KEY_CAP) ok = true;
            else if (cnt < KNN) {
                if (triedMax) break;                   // needs radius > hs*h -> ladder
                tau = taumax; triedMax = true;
            } else tau *= 0.6f;
        }
        if (!ok) {                                     // rare Poisson-tail points
            knn_ladder(sortedPts, cellStart, qp, s, hs + 1, keys[wave], lane, knn_out);
            continue;
        }
        const int m = cnt;
        const unsigned long long k0 = (lane < m) ? keys[wave][lane] : ~0ull;
        const unsigned long long k1 = (lane + 64 < m) ? keys[wave][lane + 64] : ~0ull;
        int r0 = 0, r1 = 0;
        for (int j = 0; j < m; ++j) {
            const unsigned long long kj = keys[wave][j];   // LDS broadcast
            r0 += (kj < k0); r1 += (kj < k1);
        }
        if (lane < m && r0 < KNN)      knn_out[s * KNN + r0] = (int)(unsigned)(k0 & 0xffffffffull);
        if (lane + 64 < m && r1 < KNN) knn_out[s * KNN + r1] = (int)(unsigned)(k1 & 0xffffffffull);
    }
}

// ---------------------------------------------------------------------------
// CRF iteration, SORTED space, 8 lanes/point (round-8 verified).
// ---------------------------------------------------------------------------
__global__ __launch_bounds__(256) void crf_iter_kernel(const float* __restrict__ ls,
                                                       const float* __restrict__ W,
                                                       const int* __restrict__ knn,
                                                       const float* __restrict__ qin,
                                                       float* __restrict__ qout,
                                                       const int* __restrict__ orig,
                                                       float* __restrict__ outRef,
                                                       float* __restrict__ outQ) {
    __shared__ float Ws[NCLS * NCLS];
    for (int i = threadIdx.x; i < NCLS * NCLS; i += blockDim.x) Ws[i] = W[i];
    __syncthreads();
    const int t = blockIdx.x * blockDim.x + threadIdx.x;
    const int p = t >> 3;
    const int sub = t & 7;
    if (p >= N_PTS) return;

    float acc[NCLS];
#pragma unroll
    for (int c = 0; c < NCLS; ++c) acc[c] = 0.f;

    const int2 k2 = ((const int2*)(knn + p * KNN))[sub];
    const int ids[2] = {k2.x, k2.y};
#pragma unroll
    for (int u = 0; u < 2; ++u) {
        unsigned id = (unsigned)ids[u];
        if (id >= N_PTS) id = 0;        // safety clamp (unreachable)
        const float4* r4 = (const float4*)(qin + id * NCLS);
#pragma unroll
        for (int v = 0; v < 5; ++v) {
            const float4 a = r4[v];
            acc[4 * v + 0] += a.x; acc[4 * v + 1] += a.y;
            acc[4 * v + 2] += a.z; acc[4 * v + 3] += a.w;
        }
    }
#pragma unroll
    for (int c = 0; c < NCLS; ++c) {
        acc[c] += __shfl_xor(acc[c], 1, 64);
        acc[c] += __shfl_xor(acc[c], 2, 64);
        acc[c] += __shfl_xor(acc[c], 4, 64);
        acc[c] *= (1.f / 16.f);          // msg (sum over all 16 neighbours)
    }

    const int c0 = (sub & 3) * 5;        // sub and sub+4 duplicate this block
    float ref[5];
#pragma unroll
    for (int i = 0; i < 5; ++i) {
        float s = ls[p * NCLS + c0 + i];
#pragma unroll
        for (int k = 0; k < NCLS; ++k) s += acc[k] * Ws[(c0 + i) * NCLS + k];  // x@W^T
        ref[i] = s;
    }

    float mx = ref[0];
#pragma unroll
    for (int i = 1; i < 5; ++i) mx = fmaxf(mx, ref[i]);
    mx = fmaxf(mx, __shfl_xor(mx, 1, 64));   // halves hold identical values,
    mx = fmaxf(mx, __shfl_xor(mx, 2, 64));   // so xor1,2 gives the full max
    float ex[5];
    float ps = 0.f;
#pragma unroll
    for (int i = 0; i < 5; ++i) { ex[i] = __expf(ref[i] - mx); ps += ex[i]; }
    ps += __shfl_xor(ps, 1, 64);
    ps += __shfl_xor(ps, 2, 64);
    const float inv = 1.f / ps;

    if (sub < 4) {                        // mirror half skips stores
        if (outRef != nullptr) {
            const int o = orig[p];
#pragma unroll
            for (int i = 0; i < 5; ++i) {
                outRef[o * NCLS + c0 + i] = ref[i];
                outQ[o * NCLS + c0 + i] = ex[i] * inv;
            }
        } else {
#pragma unroll
            for (int i = 0; i < 5; ++i) qout[p * NCLS + c0 + i] = ex[i] * inv;
        }
    }
}

// ---------------------------------------------------------------------------
extern "C" void kernel_launch(void* const* d_in, const int* in_sizes, int n_in,
                              void* d_out, int out_size, void* d_ws, size_t ws_size,
                              hipStream_t stream) {
    const float* logits = (const float*)d_in[0];   // (20000, 20)
    const float* coords = (const float*)d_in[1];   // (20000, 3)
    const float* W      = (const float*)d_in[2];   // (20, 20)
    float* out = (float*)d_out;                    // refined (400000) | q (400000)

    // workspace (~5 MB); q1s aliases out's q-region (safe: final pass reads
    // only q0s/ls/knn/orig and overwrites that region last).
    char* ws = (char*)d_ws;
    size_t off = 0;
    int* knn = (int*)(ws + off);              off += (size_t)N_PTS * KNN * 4;
    off = (off + 255) & ~(size_t)255;
    float* ls = (float*)(ws + off);           off += (size_t)N_PTS * NCLS * 4;
    off = (off + 255) & ~(size_t)255;
    float* q0s = (float*)(ws + off);          off += (size_t)N_PTS * NCLS * 4;
    off = (off + 255) & ~(size_t)255;
    float4* sortedPts = (float4*)(ws + off);  off += (size_t)N_PTS * 16;
    off = (off + 255) & ~(size_t)255;
    int* orig = (int*)(ws + off);             off += (size_t)N_PTS * 4;
    off = (off + 255) & ~(size_t)255;
    int* cellCount = (int*)(ws + off);        off += (size_t)(NCELLS + 2) * 4;
    int* doneCtr   = cellCount + NCELLS;      // zeroed with cellCount
    int* readyFlag = cellCount + NCELLS + 1;  // zeroed with cellCount
    off = (off + 255) & ~(size_t)255;
    int* cellStart = (int*)(ws + off);        off += (size_t)(NCELLS + 1) * 4;
    off = (off + 255) & ~(size_t)255;
    int* cellCursor = (int*)(ws + off);
    float* q1s = out + N_PTS * NCLS;

    const int threads = 256;
    const int pblocks = (N_PTS + threads - 1) / threads;      // 79
    const int cblocks = (8 * N_PTS + threads - 1) / threads;  // 625 (8 lanes/pt)

    hipMemsetAsync(cellCount, 0, (NCELLS + 2) * sizeof(int), stream);
    build_kernel<<<pblocks, threads, 0, stream>>>(coords, logits, cellCount, doneCtr,
                                                  readyFlag, cellStart, cellCursor,
                                                  sortedPts, orig, ls, q0s);
    knn_kernel<<<NCELLS, threads, 0, stream>>>(sortedPts, cellStart, knn);
    crf_iter_kernel<<<cblocks, threads, 0, stream>>>(ls, W, knn, q0s, q1s, orig,
                                                     nullptr, nullptr);
    crf_iter_kernel<<<cblocks, threads, 0, stream>>>(ls, W, knn, q1s, q0s, orig,
                                                     nullptr, nullptr);
    crf_iter_kernel<<<cblocks, threads, 0, stream>>>(ls, W, knn, q0s, nullptr, orig,
                                                     out, out + N_PTS * NCLS);
}